// Round 2
// baseline (24971.933 us; speedup 1.0000x reference)
//
#include <hip/hip_runtime.h>

#define BATCH 32
#define HID   512
#define EMB   512
#define VOCAB 50257
#define TSTEPS 64
#define JT2   64            // columns per logits block
#define G2    786           // grid size = ceil(VOCAB / JT2)

// ---------------------------------------------------------------------------
// Monotonic signal/wait (device scope). sig: whole block's prior work is
// made globally visible, then +1. waitge: spin until counter >= target,
// then acquire-fence (invalidates L1/L2 so we re-read other XCDs' writes).
// Monotonic counters never reset -> no reuse races across the 64 steps.
// ---------------------------------------------------------------------------
__device__ __forceinline__ void sig(int* ctr) {
    __syncthreads();                 // all lanes' stores issued & vm-drained
    if (threadIdx.x == 0) {
        __threadfence();             // release: wbl2 to coherence point
        __hip_atomic_fetch_add(ctr, 1, __ATOMIC_RELEASE, __HIP_MEMORY_SCOPE_AGENT);
    }
}
__device__ __forceinline__ void waitge(int* ctr, int target) {
    if (threadIdx.x == 0) {
        while (__hip_atomic_load(ctr, __ATOMIC_RELAXED, __HIP_MEMORY_SCOPE_AGENT) < target)
            __builtin_amdgcn_s_sleep(2);
        __threadfence();             // acquire: invalidate L1/L2
    }
    __syncthreads();
}

// ---------------------------------------------------------------------------
// small_gemm: outT = [tanh](inA @ WA [+ inB @ WB] + bias), feature-major.
// One block (g in [0,32)) owns 16 output cols; tid = ks*16+jl, ks slices
// K=512 into 32-wide chunks. Identical math to the standalone k_small.
// ---------------------------------------------------------------------------
__device__ void small_gemm(const float* __restrict__ inA, const float* __restrict__ WA,
                           const float* __restrict__ inB, const float* __restrict__ WB,
                           const float* __restrict__ bias,
                           float* __restrict__ outT, float* __restrict__ hout,
                           int t, int do_tanh, int g, float* part /*32*257*/) {
    int tid = threadIdx.x;
    int j0 = g * 16;
    int jl = tid & 15, ks = tid >> 4;
    int k0 = ks * 32;
    int j = j0 + jl;

    float acc[32];
#pragma unroll
    for (int b = 0; b < 32; b++) acc[b] = 0.f;

    const float4* A4 = (const float4*)inA;
    if (inB != nullptr) {
        const float4* B4 = (const float4*)inB;
        for (int kk = 0; kk < 32; kk++) {
            int k = k0 + kk;
            float wa = WA[k * HID + j];
            float wb = WB[k * HID + j];
#pragma unroll
            for (int q = 0; q < 8; q++) {
                float4 a  = A4[k * 8 + q];
                float4 bv = B4[k * 8 + q];
                acc[q*4+0] = fmaf(a.x,  wa, acc[q*4+0]);
                acc[q*4+1] = fmaf(a.y,  wa, acc[q*4+1]);
                acc[q*4+2] = fmaf(a.z,  wa, acc[q*4+2]);
                acc[q*4+3] = fmaf(a.w,  wa, acc[q*4+3]);
                acc[q*4+0] = fmaf(bv.x, wb, acc[q*4+0]);
                acc[q*4+1] = fmaf(bv.y, wb, acc[q*4+1]);
                acc[q*4+2] = fmaf(bv.z, wb, acc[q*4+2]);
                acc[q*4+3] = fmaf(bv.w, wb, acc[q*4+3]);
            }
        }
    } else {
        for (int kk = 0; kk < 32; kk++) {
            int k = k0 + kk;
            float wa = WA[k * HID + j];
#pragma unroll
            for (int q = 0; q < 8; q++) {
                float4 a = A4[k * 8 + q];
                acc[q*4+0] = fmaf(a.x, wa, acc[q*4+0]);
                acc[q*4+1] = fmaf(a.y, wa, acc[q*4+1]);
                acc[q*4+2] = fmaf(a.z, wa, acc[q*4+2]);
                acc[q*4+3] = fmaf(a.w, wa, acc[q*4+3]);
            }
        }
    }

#pragma unroll
    for (int b = 0; b < 32; b++) part[b * 257 + tid] = acc[b];
    __syncthreads();

#pragma unroll
    for (int i = 0; i < 2; i++) {
        int o = i * 256 + tid;
        int jlo = o >> 5, bo = o & 31;
        float s = 0.f;
#pragma unroll
        for (int k2 = 0; k2 < 16; k2++) s += part[bo * 257 + k2 * 16 + jlo];
        s += bias[j0 + jlo];
        if (do_tanh) s = tanhf(s);
        outT[(j0 + jlo) * 32 + bo] = s;
        if (hout != nullptr)
            hout[(size_t)bo * (TSTEPS * HID) + (size_t)t * HID + (j0 + jlo)] = s;
    }
}

// ---------------------------------------------------------------------------
// sm0_body: x1T = tanh(softmax_row(z0T)) for batch row b. 256 threads.
// ---------------------------------------------------------------------------
__device__ void sm0_body(const float* __restrict__ z0T, float* __restrict__ x1T,
                         float* shm, int b) {
    float* red = shm;
    int tid = threadIdx.x;
    float v0 = z0T[tid * 32 + b];
    float v1 = z0T[(tid + 256) * 32 + b];
    red[tid] = fmaxf(v0, v1);
    __syncthreads();
    for (int s = 128; s > 0; s >>= 1) {
        if (tid < s) red[tid] = fmaxf(red[tid], red[tid + s]);
        __syncthreads();
    }
    float M = red[0];
    __syncthreads();
    float e0 = expf(v0 - M), e1 = expf(v1 - M);
    red[tid] = e0 + e1;
    __syncthreads();
    for (int s = 128; s > 0; s >>= 1) {
        if (tid < s) red[tid] += red[tid + s];
        __syncthreads();
    }
    float inv = 1.0f / red[0];
    x1T[tid * 32 + b]         = tanhf(e0 * inv);
    x1T[(tid + 256) * 32 + b] = tanhf(e1 * inv);
}

// ---------------------------------------------------------------------------
// comb_body: merge 786 partials for batch row b -> M, Sinv (ws), argmax
// (first-occurrence tie-break), embed next token into xT.
// ---------------------------------------------------------------------------
__device__ void comb_body(const float* __restrict__ pmax, const float* __restrict__ psum,
                          const int* __restrict__ parg,
                          float* __restrict__ Mws, float* __restrict__ Sinvws,
                          const float* __restrict__ emb, float* __restrict__ xT,
                          float* shm, int b) {
    float* redm  = shm;                 // 256
    float* reds  = shm + 256;           // 256
    int*   redc  = (int*)(shm + 512);   // 256
    int*   toksh = (int*)(shm + 768);   // 1
    int tid = threadIdx.x;

    float m = -1e30f;
    for (int g = tid; g < G2; g += 256) m = fmaxf(m, pmax[b * G2 + g]);
    redm[tid] = m;
    __syncthreads();
    for (int s = 128; s > 0; s >>= 1) {
        if (tid < s) redm[tid] = fmaxf(redm[tid], redm[tid + s]);
        __syncthreads();
    }
    float M = redm[0];

    float s_l = 0.f;
    int c_l = 0x7fffffff;
    for (int g = tid; g < G2; g += 256) {
        float pm = pmax[b * G2 + g];
        s_l += psum[b * G2 + g] * expf(pm - M);
        if (pm == M) c_l = min(c_l, parg[b * G2 + g]);
    }
    reds[tid] = s_l;
    redc[tid] = c_l;
    __syncthreads();
    for (int s = 128; s > 0; s >>= 1) {
        if (tid < s) {
            reds[tid] += reds[tid + s];
            redc[tid] = min(redc[tid], redc[tid + s]);
        }
        __syncthreads();
    }
    if (tid == 0) {
        Mws[b] = M;
        Sinvws[b] = 1.0f / reds[0];
        toksh[0] = redc[0];
    }
    __syncthreads();
    int tok = toksh[0];
    for (int e = tid; e < HID; e += 256)
        xT[e * 32 + b] = emb[(size_t)tok * EMB + e];
}

// ---------------------------------------------------------------------------
// z1_body: logits tile g (64 cols) = h1 @ V1 + c1; raw store + per-tile
// softmax partials; overlapped normalization of step t-1's y.
// Identical math to the round-1 k_z1.
// ---------------------------------------------------------------------------
__device__ void z1_body(const float* __restrict__ h1T, const float* __restrict__ V1w,
                        const float* __restrict__ c1, float* __restrict__ yout,
                        float* __restrict__ pmax, float* __restrict__ psum,
                        int* __restrict__ parg,
                        const float* __restrict__ Mws, const float* __restrict__ Sinvws,
                        int t, int do_ywr, int g, float* partz /*32*256*/) {
    int tid = threadIdx.x;
    int j0 = g * JT2;
    int jl = tid & 63, ks = tid >> 6;
    int k0 = ks * 128;
    int jv = j0 + jl;
    int jc = jv < VOCAB ? jv : (VOCAB - 1);

    // issue prior-step y loads early; finished after the matmul
    float yv[8];
    if (do_ywr) {
#pragma unroll
        for (int i = 0; i < 8; i++) {
            int o = i * 256 + tid;
            int bo = o >> 6;
            int jj = j0 + (o & 63);
            if (jj < VOCAB)
                yv[i] = yout[((size_t)bo * TSTEPS + (t - 1)) * VOCAB + jj];
        }
    }

    float acc[32];
#pragma unroll
    for (int b = 0; b < 32; b++) acc[b] = 0.f;

    const float4* h4 = (const float4*)h1T;
    const float*  vp = V1w + (size_t)k0 * VOCAB + jc;
    for (int kk = 0; kk < 128; kk += 8) {
        float v[8];
#pragma unroll
        for (int u = 0; u < 8; u++) v[u] = vp[(size_t)(kk + u) * VOCAB];
#pragma unroll
        for (int u = 0; u < 8; u++) {
            int kb = __builtin_amdgcn_readfirstlane(k0 + kk + u) * 8;
            float4 hq[4];
#pragma unroll
            for (int q = 0; q < 4; q++) hq[q] = h4[kb + q];
#pragma unroll
            for (int q = 0; q < 4; q++) {
                acc[q*4+0] = fmaf(hq[q].x, v[u], acc[q*4+0]);
                acc[q*4+1] = fmaf(hq[q].y, v[u], acc[q*4+1]);
                acc[q*4+2] = fmaf(hq[q].z, v[u], acc[q*4+2]);
                acc[q*4+3] = fmaf(hq[q].w, v[u], acc[q*4+3]);
            }
#pragma unroll
            for (int q = 0; q < 4; q++) hq[q] = h4[kb + 4 + q];
#pragma unroll
            for (int q = 0; q < 4; q++) {
                acc[16+q*4+0] = fmaf(hq[q].x, v[u], acc[16+q*4+0]);
                acc[16+q*4+1] = fmaf(hq[q].y, v[u], acc[16+q*4+1]);
                acc[16+q*4+2] = fmaf(hq[q].z, v[u], acc[16+q*4+2]);
                acc[16+q*4+3] = fmaf(hq[q].w, v[u], acc[16+q*4+3]);
            }
        }
    }

#pragma unroll
    for (int b = 0; b < 32; b++) partz[b * 256 + tid] = acc[b];

    // finish y normalization for step t-1 (independent of the barrier)
    if (do_ywr) {
#pragma unroll
        for (int i = 0; i < 8; i++) {
            int o = i * 256 + tid;
            int bo = o >> 6;
            int jj = j0 + (o & 63);
            if (jj < VOCAB)
                yout[((size_t)bo * TSTEPS + (t - 1)) * VOCAB + jj]
                    = expf(yv[i] - Mws[bo]) * Sinvws[bo];
        }
    }
    __syncthreads();

    // combine 4 K-slices, add bias, store raw logits; wave-butterfly stats
    int w = tid >> 6;
#pragma unroll
    for (int i = 0; i < 8; i++) {
        int bo = i * 4 + w;
        float s = partz[bo * 256 + jl]
                + partz[bo * 256 + 64 + jl]
                + partz[bo * 256 + 128 + jl]
                + partz[bo * 256 + 192 + jl];
        int jj = j0 + jl;
        float z;
        if (jj < VOCAB) {
            z = s + c1[jj];
            yout[((size_t)bo * TSTEPS + t) * VOCAB + jj] = z;
        } else {
            z = -1e30f;
        }
        float m = z; int a = jj;
#pragma unroll
        for (int d = 1; d < 64; d <<= 1) {
            float mo = __shfl_xor(m, d);
            int   ao = __shfl_xor(a, d);
            if (mo > m || (mo == m && ao < a)) { m = mo; a = ao; }
        }
        float e = expf(z - m);
        float ss = e;
#pragma unroll
        for (int d = 1; d < 64; d <<= 1) ss += __shfl_xor(ss, d);
        if (jl == 0) {
            pmax[bo * G2 + g] = m;
            psum[bo * G2 + g] = ss;
            parg[bo * G2 + g] = a;
        }
    }
}

// ---------------------------------------------------------------------------
// k_all: the entire 64-step decode in ONE persistent kernel.
// Grid 786 x 256. Co-residency guaranteed: LDS 32,896 B (<=40,960) and
// __launch_bounds__(256,4) -> 4 blocks/CU -> 1024 slots >= 786 blocks.
// Blocks 0-31: recurrent chain (comb/h0/z0/sm0/h1) with 32-block sub-
// barriers; all blocks: z1 tile. Two monotonic counters order the phases.
// ---------------------------------------------------------------------------
__global__ __launch_bounds__(256, 4) void k_all(
    const int* __restrict__ x, const float* __restrict__ h_prev,
    const float* __restrict__ emb,
    const float* __restrict__ U0, const float* __restrict__ W0, const float* __restrict__ b0,
    const float* __restrict__ V0, const float* __restrict__ c0,
    const float* __restrict__ U1, const float* __restrict__ W1, const float* __restrict__ b1,
    const float* __restrict__ V1, const float* __restrict__ c1,
    float* __restrict__ hout, float* __restrict__ yout,
    float* xT, float* h0Ta, float* h0Tb, float* h1Ta, float* h1Tb,
    float* z0T, float* x1T,
    float* pmax, float* psum, int* parg,
    float* Mws, float* Sinvws, int* bar)
{
    __shared__ float shm[32 * 257];
    const int blk = blockIdx.x;
    const int tid = threadIdx.x;
    int* done_chain = bar + 0;   // +32 per chain step (and final comb)
    int* done_z1    = bar + 1;   // +786 per z1 phase
    int* subc       = bar + 2;   // 32-block sub-barrier, monotonic
    int nsub = 0;

    if (blk < 32) {
        int b = blk;
        int tok = x[b];
        for (int e = tid; e < HID; e += 256) {
            xT[e * 32 + b] = emb[(size_t)tok * EMB + e];
            float hp = h_prev[b * HID + e];
            h0Ta[e * 32 + b] = hp;
            h1Ta[e * 32 + b] = hp;
        }
        nsub++; sig(subc); waitge(subc, 32 * nsub);
    }

    for (int t = 0; t < TSTEPS; t++) {
        float* h0p = (t & 1) ? h0Tb : h0Ta;
        float* h0n = (t & 1) ? h0Ta : h0Tb;
        float* h1p = (t & 1) ? h1Tb : h1Ta;
        float* h1n = (t & 1) ? h1Ta : h1Tb;

        if (blk < 32) {
            if (t > 0) {
                waitge(done_z1, G2 * t);       // all of step t-1's partials
                comb_body(pmax, psum, parg, Mws, Sinvws, emb, xT, shm, blk);
                nsub++; sig(subc); waitge(subc, 32 * nsub);
            }
            small_gemm(xT, U0, h0p, W0, b0, h0n, nullptr, t, 1, blk, shm);
            nsub++; sig(subc); waitge(subc, 32 * nsub);
            small_gemm(h0n, V0, nullptr, nullptr, c0, z0T, nullptr, t, 0, blk, shm);
            nsub++; sig(subc); waitge(subc, 32 * nsub);
            sm0_body(z0T, x1T, shm, blk);
            nsub++; sig(subc); waitge(subc, 32 * nsub);
            small_gemm(x1T, U1, h1p, W1, b1, h1n, hout, t, 1, blk, shm);
            sig(done_chain);
        }
        waitge(done_chain, 32 * (t + 1));      // h1(t) + Mws/Sinv(t-1) ready
        z1_body(h1n, V1, c1, yout, pmax, psum, parg, Mws, Sinvws,
                t, (t > 0) ? 1 : 0, blk, shm);
        sig(done_z1);
    }

    if (blk < 32) {
        waitge(done_z1, G2 * TSTEPS);
        comb_body(pmax, psum, parg, Mws, Sinvws, emb, xT, shm, blk);
        sig(done_chain);
    }
    waitge(done_chain, 32 * (TSTEPS + 1));
    // final normalize of step 63's y (tile g = blk)
    {
        int j0 = blk * JT2;
#pragma unroll
        for (int i = 0; i < 8; i++) {
            int o = i * 256 + tid;
            int bo = o >> 6;
            int jj = j0 + (o & 63);
            if (jj < VOCAB) {
                size_t idx = ((size_t)bo * TSTEPS + (TSTEPS - 1)) * VOCAB + jj;
                yout[idx] = expf(yout[idx] - Mws[bo]) * Sinvws[bo];
            }
        }
    }
}

// ---------------------------------------------------------------------------
extern "C" void kernel_launch(void* const* d_in, const int* in_sizes, int n_in,
                              void* d_out, int out_size, void* d_ws, size_t ws_size,
                              hipStream_t stream) {
    const int*   x      = (const int*)d_in[0];
    // d_in[1] = max_len (64), d_in[2] = eos_token_id — unused by reference math
    const float* h_prev = (const float*)d_in[3];
    const float* emb    = (const float*)d_in[4];
    const float* U0 = (const float*)d_in[5];
    const float* W0 = (const float*)d_in[6];
    const float* b0 = (const float*)d_in[7];
    const float* V0 = (const float*)d_in[8];
    const float* c0 = (const float*)d_in[9];
    const float* U1 = (const float*)d_in[10];
    const float* W1 = (const float*)d_in[11];
    const float* b1 = (const float*)d_in[12];
    const float* V1 = (const float*)d_in[13];
    const float* c1 = (const float*)d_in[14];

    float* out  = (float*)d_out;
    float* hout = out;                                   // (32, 64, 512)
    float* yout = out + (size_t)BATCH * TSTEPS * HID;    // (32, 64, 50257)

    // workspace carve (all 16B-aligned)
    float* w = (float*)d_ws;
    float* xT    = w; w += HID * 32;
    float* h0Ta  = w; w += HID * 32;
    float* h0Tb  = w; w += HID * 32;
    float* h1Ta  = w; w += HID * 32;
    float* h1Tb  = w; w += HID * 32;
    float* z0T   = w; w += HID * 32;
    float* x1T   = w; w += HID * 32;
    float* pmax  = w; w += 32 * G2;
    float* psum  = w; w += 32 * G2;
    float* Mws   = w; w += 32;
    float* Sinvws= w; w += 32;
    int*   parg  = (int*)w; w += 32 * G2;
    int*   bar   = (int*)w; w += 32;

    // zero the sync counters (re-zeroed on every graph replay)
    hipMemsetAsync(bar, 0, 4 * sizeof(int), stream);

    hipLaunchKernelGGL(k_all, dim3(G2), dim3(256), 0, stream,
                       x, h_prev, emb,
                       U0, W0, b0, V0, c0, U1, W1, b1, V1, c1,
                       hout, yout,
                       xT, h0Ta, h0Tb, h1Ta, h1Tb, z0T, x1T,
                       pmax, psum, parg, Mws, Sinvws, bar);
}

// Round 3
// 19554.285 us; speedup vs baseline: 1.2771x; 1.2771x over previous
//
#include <hip/hip_runtime.h>

#define BATCH 32
#define HID   512
#define EMB   512
#define VOCAB 50257
#define TSTEPS 64
#define JT2   64            // columns per logits block
#define G2    786           // grid size = ceil(VOCAB / JT2)
#define NSLOT (HID * 32)    // floats per ring slot (one feature-major state)

// Relaxed agent-scope (device-coherent) scalar access: store = sc1
// write-through to the coherence point (L3); load = sc1 read from L3.
// No fences anywhere -> no buffer_wbl2 / buffer_inv tag-walks (the round-2
// killer: ~1600 full-L2 tag walks per step, serialized per XCD ~ 330 us/step).
#define AST(p, v) __hip_atomic_store((p), (v), __ATOMIC_RELAXED, __HIP_MEMORY_SCOPE_AGENT)
#define ALDF(p)   __hip_atomic_load((p), __ATOMIC_RELAXED, __HIP_MEMORY_SCOPE_AGENT)

// ---------------------------------------------------------------------------
// sig: drain this block's stores (vmcnt ack => visible at L3 for sc1 stores),
// then bump the monotonic counter. waitge: poll relaxed, then __syncthreads
// (also a compiler barrier, so subsequent loads can't hoist above the poll).
// ---------------------------------------------------------------------------
__device__ __forceinline__ void sig(int* ctr) {
    asm volatile("s_waitcnt vmcnt(0) lgkmcnt(0)" ::: "memory");
    __syncthreads();
    if (threadIdx.x == 0)
        __hip_atomic_fetch_add(ctr, 1, __ATOMIC_RELAXED, __HIP_MEMORY_SCOPE_AGENT);
}
template <int SLP>
__device__ __forceinline__ void waitge(int* ctr, int target) {
    if (threadIdx.x == 0) {
        while (__hip_atomic_load(ctr, __ATOMIC_RELAXED, __HIP_MEMORY_SCOPE_AGENT) < target)
            __builtin_amdgcn_s_sleep(SLP);
    }
    __syncthreads();
}

// ---------------------------------------------------------------------------
// small_gemm: outT = [tanh](inA @ WA [+ inB @ WB] + bias), feature-major.
// Inputs read with PLAIN cached float4 loads (ring slots are write-once:
// first touch misses to L3 -> fresh; re-reads are of immutable data).
// Outputs written with coherent scalar stores (2 per thread).
// Math identical to rounds 0-2.
// ---------------------------------------------------------------------------
__device__ void small_gemm(const float* __restrict__ inA, const float* __restrict__ WA,
                           const float* __restrict__ inB, const float* __restrict__ WB,
                           const float* __restrict__ bias,
                           float* __restrict__ outT, float* __restrict__ hout,
                           int t, int do_tanh, int g, float* part /*32*257*/) {
    int tid = threadIdx.x;
    int j0 = g * 16;
    int jl = tid & 15, ks = tid >> 4;
    int k0 = ks * 32;
    int j = j0 + jl;

    float acc[32];
#pragma unroll
    for (int b = 0; b < 32; b++) acc[b] = 0.f;

    const float4* A4 = (const float4*)inA;
    if (inB != nullptr) {
        const float4* B4 = (const float4*)inB;
        for (int kk = 0; kk < 32; kk++) {
            int k = k0 + kk;
            float wa = WA[k * HID + j];
            float wb = WB[k * HID + j];
#pragma unroll
            for (int q = 0; q < 8; q++) {
                float4 a  = A4[k * 8 + q];
                float4 bv = B4[k * 8 + q];
                acc[q*4+0] = fmaf(a.x,  wa, acc[q*4+0]);
                acc[q*4+1] = fmaf(a.y,  wa, acc[q*4+1]);
                acc[q*4+2] = fmaf(a.z,  wa, acc[q*4+2]);
                acc[q*4+3] = fmaf(a.w,  wa, acc[q*4+3]);
                acc[q*4+0] = fmaf(bv.x, wb, acc[q*4+0]);
                acc[q*4+1] = fmaf(bv.y, wb, acc[q*4+1]);
                acc[q*4+2] = fmaf(bv.z, wb, acc[q*4+2]);
                acc[q*4+3] = fmaf(bv.w, wb, acc[q*4+3]);
            }
        }
    } else {
        for (int kk = 0; kk < 32; kk++) {
            int k = k0 + kk;
            float wa = WA[k * HID + j];
#pragma unroll
            for (int q = 0; q < 8; q++) {
                float4 a = A4[k * 8 + q];
                acc[q*4+0] = fmaf(a.x, wa, acc[q*4+0]);
                acc[q*4+1] = fmaf(a.y, wa, acc[q*4+1]);
                acc[q*4+2] = fmaf(a.z, wa, acc[q*4+2]);
                acc[q*4+3] = fmaf(a.w, wa, acc[q*4+3]);
            }
        }
    }

#pragma unroll
    for (int b = 0; b < 32; b++) part[b * 257 + tid] = acc[b];
    __syncthreads();

#pragma unroll
    for (int i = 0; i < 2; i++) {
        int o = i * 256 + tid;
        int jlo = o >> 5, bo = o & 31;
        float s = 0.f;
#pragma unroll
        for (int k2 = 0; k2 < 16; k2++) s += part[bo * 257 + k2 * 16 + jlo];
        s += bias[j0 + jlo];
        if (do_tanh) s = tanhf(s);
        AST(&outT[(j0 + jlo) * 32 + bo], s);
        if (hout != nullptr)
            hout[(size_t)bo * (TSTEPS * HID) + (size_t)t * HID + (j0 + jlo)] = s;
    }
    __syncthreads();   // protect shm reuse by next phase
}

// ---------------------------------------------------------------------------
// sm0_body: x1T = tanh(softmax_row(z0T)) for batch row b. 256 threads.
// z0T plain-cached read (write-once slot); x1T coherent store.
// ---------------------------------------------------------------------------
__device__ void sm0_body(const float* __restrict__ z0T, float* __restrict__ x1T,
                         float* shm, int b) {
    float* red = shm;
    int tid = threadIdx.x;
    float v0 = z0T[tid * 32 + b];
    float v1 = z0T[(tid + 256) * 32 + b];
    red[tid] = fmaxf(v0, v1);
    __syncthreads();
    for (int s = 128; s > 0; s >>= 1) {
        if (tid < s) red[tid] = fmaxf(red[tid], red[tid + s]);
        __syncthreads();
    }
    float M = red[0];
    __syncthreads();
    float e0 = expf(v0 - M), e1 = expf(v1 - M);
    red[tid] = e0 + e1;
    __syncthreads();
    for (int s = 128; s > 0; s >>= 1) {
        if (tid < s) red[tid] += red[tid + s];
        __syncthreads();
    }
    float inv = 1.0f / red[0];
    AST(&x1T[tid * 32 + b],         tanhf(e0 * inv));
    AST(&x1T[(tid + 256) * 32 + b], tanhf(e1 * inv));
    __syncthreads();
}

// ---------------------------------------------------------------------------
// comb_body: merge 786 partials for row b -> M, Sinv (coherent), argmax
// (first-occurrence tie-break), embed next token into xT (coherent stores).
// Partials are mutable cross-step buffers -> coherent loads.
// ---------------------------------------------------------------------------
__device__ void comb_body(float* __restrict__ pmax, float* __restrict__ psum,
                          int* __restrict__ parg,
                          float* __restrict__ Mws, float* __restrict__ Sinvws,
                          const float* __restrict__ emb, float* __restrict__ xT,
                          float* shm, int b) {
    float* redm  = shm;                 // 256
    float* reds  = shm + 256;           // 256
    int*   redc  = (int*)(shm + 512);   // 256
    int*   toksh = (int*)(shm + 768);   // 1
    int tid = threadIdx.x;

    float m = -1e30f;
    for (int g = tid; g < G2; g += 256) m = fmaxf(m, ALDF(&pmax[b * G2 + g]));
    redm[tid] = m;
    __syncthreads();
    for (int s = 128; s > 0; s >>= 1) {
        if (tid < s) redm[tid] = fmaxf(redm[tid], redm[tid + s]);
        __syncthreads();
    }
    float M = redm[0];

    float s_l = 0.f;
    int c_l = 0x7fffffff;
    for (int g = tid; g < G2; g += 256) {
        float pm = ALDF(&pmax[b * G2 + g]);
        s_l += ALDF(&psum[b * G2 + g]) * expf(pm - M);
        if (pm == M) c_l = min(c_l, __hip_atomic_load(&parg[b * G2 + g],
                               __ATOMIC_RELAXED, __HIP_MEMORY_SCOPE_AGENT));
    }
    reds[tid] = s_l;
    redc[tid] = c_l;
    __syncthreads();
    for (int s = 128; s > 0; s >>= 1) {
        if (tid < s) {
            reds[tid] += reds[tid + s];
            redc[tid] = min(redc[tid], redc[tid + s]);
        }
        __syncthreads();
    }
    if (tid == 0) {
        AST(&Mws[b], M);
        AST(&Sinvws[b], 1.0f / reds[0]);
        toksh[0] = redc[0];
    }
    __syncthreads();
    int tok = toksh[0];
    for (int e = tid; e < HID; e += 256)
        AST(&xT[e * 32 + b], emb[(size_t)tok * EMB + e]);
    __syncthreads();
}

// ---------------------------------------------------------------------------
// z1_body: logits tile g = h1 @ V1 + c1; raw store + per-tile softmax
// partials (coherent); overlapped normalization of step t-1's y.
// h1T / V1 / c1 / yout: PLAIN cached (h1T slot is write-once; V1 read-only
// and never invalidated -> stays L2/L3 resident; yout rows are same-block).
// Math identical to rounds 1-2.
// ---------------------------------------------------------------------------
__device__ void z1_body(const float* __restrict__ h1T, const float* __restrict__ V1w,
                        const float* __restrict__ c1, float* __restrict__ yout,
                        float* __restrict__ pmax, float* __restrict__ psum,
                        int* __restrict__ parg,
                        float* __restrict__ Mws, float* __restrict__ Sinvws,
                        int t, int do_ywr, int g, float* partz /*32*256*/) {
    int tid = threadIdx.x;
    int j0 = g * JT2;
    int jl = tid & 63, ks = tid >> 6;
    int k0 = ks * 128;
    int jv = j0 + jl;
    int jc = jv < VOCAB ? jv : (VOCAB - 1);

    // issue prior-step y loads early; finished after the matmul
    float yv[8];
    if (do_ywr) {
#pragma unroll
        for (int i = 0; i < 8; i++) {
            int o = i * 256 + tid;
            int bo = o >> 6;
            int jj = j0 + (o & 63);
            if (jj < VOCAB)
                yv[i] = yout[((size_t)bo * TSTEPS + (t - 1)) * VOCAB + jj];
        }
    }

    float acc[32];
#pragma unroll
    for (int b = 0; b < 32; b++) acc[b] = 0.f;

    const float4* h4 = (const float4*)h1T;
    const float*  vp = V1w + (size_t)k0 * VOCAB + jc;
    for (int kk = 0; kk < 128; kk += 8) {
        float v[8];
#pragma unroll
        for (int u = 0; u < 8; u++) v[u] = vp[(size_t)(kk + u) * VOCAB];
#pragma unroll
        for (int u = 0; u < 8; u++) {
            int kb = __builtin_amdgcn_readfirstlane(k0 + kk + u) * 8;
            float4 hq[4];
#pragma unroll
            for (int q = 0; q < 4; q++) hq[q] = h4[kb + q];
#pragma unroll
            for (int q = 0; q < 4; q++) {
                acc[q*4+0] = fmaf(hq[q].x, v[u], acc[q*4+0]);
                acc[q*4+1] = fmaf(hq[q].y, v[u], acc[q*4+1]);
                acc[q*4+2] = fmaf(hq[q].z, v[u], acc[q*4+2]);
                acc[q*4+3] = fmaf(hq[q].w, v[u], acc[q*4+3]);
            }
#pragma unroll
            for (int q = 0; q < 4; q++) hq[q] = h4[kb + 4 + q];
#pragma unroll
            for (int q = 0; q < 4; q++) {
                acc[16+q*4+0] = fmaf(hq[q].x, v[u], acc[16+q*4+0]);
                acc[16+q*4+1] = fmaf(hq[q].y, v[u], acc[16+q*4+1]);
                acc[16+q*4+2] = fmaf(hq[q].z, v[u], acc[16+q*4+2]);
                acc[16+q*4+3] = fmaf(hq[q].w, v[u], acc[16+q*4+3]);
            }
        }
    }

#pragma unroll
    for (int b = 0; b < 32; b++) partz[b * 256 + tid] = acc[b];

    // finish y normalization for step t-1 (independent of the barrier)
    if (do_ywr) {
#pragma unroll
        for (int i = 0; i < 8; i++) {
            int o = i * 256 + tid;
            int bo = o >> 6;
            int jj = j0 + (o & 63);
            if (jj < VOCAB)
                yout[((size_t)bo * TSTEPS + (t - 1)) * VOCAB + jj]
                    = expf(yv[i] - ALDF(&Mws[bo])) * ALDF(&Sinvws[bo]);
        }
    }
    __syncthreads();

    // combine 4 K-slices, add bias, store raw logits; wave-butterfly stats
    int w = tid >> 6;
#pragma unroll
    for (int i = 0; i < 8; i++) {
        int bo = i * 4 + w;
        float s = partz[bo * 256 + jl]
                + partz[bo * 256 + 64 + jl]
                + partz[bo * 256 + 128 + jl]
                + partz[bo * 256 + 192 + jl];
        int jj = j0 + jl;
        float z;
        if (jj < VOCAB) {
            z = s + c1[jj];
            yout[((size_t)bo * TSTEPS + t) * VOCAB + jj] = z;
        } else {
            z = -1e30f;
        }
        float m = z; int a = jj;
#pragma unroll
        for (int d = 1; d < 64; d <<= 1) {
            float mo = __shfl_xor(m, d);
            int   ao = __shfl_xor(a, d);
            if (mo > m || (mo == m && ao < a)) { m = mo; a = ao; }
        }
        float e = expf(z - m);
        float ss = e;
#pragma unroll
        for (int d = 1; d < 64; d <<= 1) ss += __shfl_xor(ss, d);
        if (jl == 0) {
            AST(&pmax[bo * G2 + g], m);
            AST(&psum[bo * G2 + g], ss);
            __hip_atomic_store(&parg[bo * G2 + g], a,
                               __ATOMIC_RELAXED, __HIP_MEMORY_SCOPE_AGENT);
        }
    }
    __syncthreads();   // protect partz reuse
}

// ---------------------------------------------------------------------------
// k_all: entire 64-step decode in ONE persistent kernel, fence-free.
// Grid 786 x 256; LDS 32,896 B; __launch_bounds__(256,4) -> 4 blocks/CU
// -> 1024 slots >= 786 (co-residency guaranteed, no deadlock).
// Cross-block state flows through WRITE-ONCE ring slots (t-indexed, no
// wraparound within a launch) -> consumers' plain cached loads are always
// first-touch-fresh; producers write-through with sc1 scalar stores.
// ---------------------------------------------------------------------------
__global__ __launch_bounds__(256, 4) void k_all(
    const int* __restrict__ x, const float* __restrict__ h_prev,
    const float* __restrict__ emb,
    const float* __restrict__ U0, const float* __restrict__ W0, const float* __restrict__ b0,
    const float* __restrict__ V0, const float* __restrict__ c0,
    const float* __restrict__ U1, const float* __restrict__ W1, const float* __restrict__ b1,
    const float* __restrict__ V1, const float* __restrict__ c1,
    float* __restrict__ hout, float* __restrict__ yout,
    float* xTr, float* h0r, float* h1r, float* z0r, float* x1r,
    float* pmax, float* psum, int* parg,
    float* Mws, float* Sinvws, int* bar)
{
    __shared__ float shm[32 * 257];
    const int blk = blockIdx.x;
    const int tid = threadIdx.x;
    int* done_chain = bar + 0;   // +32 per chain step (and final comb)
    int* done_z1    = bar + 1;   // +786 per z1 phase
    int* subc       = bar + 2;   // 32-block sub-barrier, monotonic
    int nsub = 0;

    if (blk < 32) {
        int b = blk;
        int tok = x[b];
        for (int e = tid; e < HID; e += 256) {
            AST(&xTr[e * 32 + b], emb[(size_t)tok * EMB + e]);   // xT slot 0
            float hp = h_prev[b * HID + e];
            AST(&h0r[e * 32 + b], hp);                           // h0 slot 0
            AST(&h1r[e * 32 + b], hp);                           // h1 slot 0
        }
        nsub++; sig(subc); waitge<1>(subc, 32 * nsub);
    }

    for (int t = 0; t < TSTEPS; t++) {
        float* xT_t = xTr + (size_t)t * NSLOT;
        float* h0p  = h0r + (size_t)t * NSLOT;
        float* h0n  = h0r + (size_t)(t + 1) * NSLOT;
        float* h1p  = h1r + (size_t)t * NSLOT;
        float* h1n  = h1r + (size_t)(t + 1) * NSLOT;
        float* z0t  = z0r + (size_t)t * NSLOT;
        float* x1t  = x1r + (size_t)t * NSLOT;

        if (blk < 32) {
            if (t > 0) {
                waitge<8>(done_z1, G2 * t);      // all of step t-1's partials
                comb_body(pmax, psum, parg, Mws, Sinvws, emb, xT_t, shm, blk);
                nsub++; sig(subc); waitge<1>(subc, 32 * nsub);
            }
            small_gemm(xT_t, U0, h0p, W0, b0, h0n, nullptr, t, 1, blk, shm);
            nsub++; sig(subc); waitge<1>(subc, 32 * nsub);
            small_gemm(h0n, V0, nullptr, nullptr, c0, z0t, nullptr, t, 0, blk, shm);
            nsub++; sig(subc); waitge<1>(subc, 32 * nsub);
            sm0_body(z0t, x1t, shm, blk);
            nsub++; sig(subc); waitge<1>(subc, 32 * nsub);
            small_gemm(x1t, U1, h1p, W1, b1, h1n, hout, t, 1, blk, shm);
            sig(done_chain);
        }
        waitge<16>(done_chain, 32 * (t + 1));    // h1(t) + Mws/Sinv(t-1) ready
        z1_body(h1n, V1, c1, yout, pmax, psum, parg, Mws, Sinvws,
                t, (t > 0) ? 1 : 0, blk, shm);
        sig(done_z1);
    }

    if (blk < 32) {
        waitge<8>(done_z1, G2 * TSTEPS);
        // final comb: only Mws/Sinv needed; xT slot 64 is a scratch slot
        comb_body(pmax, psum, parg, Mws, Sinvws, emb,
                  xTr + (size_t)TSTEPS * NSLOT, shm, blk);
        sig(done_chain);
    }
    waitge<16>(done_chain, 32 * (TSTEPS + 1));
    // final normalize of step 63's y (tile g = blk; same rows this block wrote)
    {
        int j0 = blk * JT2;
#pragma unroll
        for (int i = 0; i < 8; i++) {
            int o = i * 256 + tid;
            int bo = o >> 6;
            int jj = j0 + (o & 63);
            if (jj < VOCAB) {
                size_t idx = ((size_t)bo * TSTEPS + (TSTEPS - 1)) * VOCAB + jj;
                yout[idx] = expf(yout[idx] - ALDF(&Mws[bo])) * ALDF(&Sinvws[bo]);
            }
        }
    }
}

// ---------------------------------------------------------------------------
extern "C" void kernel_launch(void* const* d_in, const int* in_sizes, int n_in,
                              void* d_out, int out_size, void* d_ws, size_t ws_size,
                              hipStream_t stream) {
    const int*   x      = (const int*)d_in[0];
    // d_in[1] = max_len (64), d_in[2] = eos_token_id — unused by reference math
    const float* h_prev = (const float*)d_in[3];
    const float* emb    = (const float*)d_in[4];
    const float* U0 = (const float*)d_in[5];
    const float* W0 = (const float*)d_in[6];
    const float* b0 = (const float*)d_in[7];
    const float* V0 = (const float*)d_in[8];
    const float* c0 = (const float*)d_in[9];
    const float* U1 = (const float*)d_in[10];
    const float* W1 = (const float*)d_in[11];
    const float* b1 = (const float*)d_in[12];
    const float* V1 = (const float*)d_in[13];
    const float* c1 = (const float*)d_in[14];

    float* out  = (float*)d_out;
    float* hout = out;                                   // (32, 64, 512)
    float* yout = out + (size_t)BATCH * TSTEPS * HID;    // (32, 64, 50257)

    // workspace carve: write-once rings (t-indexed, no wrap within a launch)
    float* w = (float*)d_ws;
    float* xTr  = w; w += (size_t)(TSTEPS + 1) * NSLOT;  // slots 0..64
    float* h0r  = w; w += (size_t)(TSTEPS + 1) * NSLOT;
    float* h1r  = w; w += (size_t)(TSTEPS + 1) * NSLOT;
    float* z0r  = w; w += (size_t)TSTEPS * NSLOT;        // slots 0..63
    float* x1r  = w; w += (size_t)TSTEPS * NSLOT;
    float* pmax = w; w += 32 * G2;
    float* psum = w; w += 32 * G2;
    float* Mws  = w; w += 32;
    float* Sinvws = w; w += 32;
    int*   parg = (int*)w; w += 32 * G2;
    int*   bar  = (int*)w; w += 32;

    // zero the sync counters (re-zeroed on every graph replay)
    hipMemsetAsync(bar, 0, 4 * sizeof(int), stream);

    hipLaunchKernelGGL(k_all, dim3(G2), dim3(256), 0, stream,
                       x, h_prev, emb,
                       U0, W0, b0, V0, c0, U1, W1, b1, V1, c1,
                       hout, yout,
                       xTr, h0r, h1r, z0r, x1r,
                       pmax, psum, parg, Mws, Sinvws, bar);
}

// Round 4
// 16781.178 us; speedup vs baseline: 1.4881x; 1.1653x over previous
//
#include <hip/hip_runtime.h>

#define BATCH 32
#define HID   512
#define EMB   512
#define VOCAB 50257
#define TSTEPS 64
#define JT2   64            // columns per logits block
#define G2    786           // grid size = ceil(VOCAB / JT2)
#define NSLOT (HID * 32)    // floats per ring slot (one feature-major state)
#define FPAD  32            // ints per flag line (128 B) -> 1 line per flag

// Relaxed agent-scope (device-coherent) scalar access (sc1 to/from L3).
// NO fences anywhere (round-2 lesson: wbl2/inv tag-walks = 330 us/step).
// Round-3 lesson: contention, not scope, was the cost -> every flag gets
// its OWN 128-B line and (where possible) its own single poller.
#define AST(p, v)  __hip_atomic_store((p), (v), __ATOMIC_RELAXED, __HIP_MEMORY_SCOPE_AGENT)
#define ASTI(p, v) __hip_atomic_store((p), (v), __ATOMIC_RELAXED, __HIP_MEMORY_SCOPE_AGENT)
#define ALDF(p)    __hip_atomic_load((p), __ATOMIC_RELAXED, __HIP_MEMORY_SCOPE_AGENT)
#define ALDI(p)    __hip_atomic_load((p), __ATOMIC_RELAXED, __HIP_MEMORY_SCOPE_AGENT)

// drain this block's stores so they are at the coherence point before a flag
__device__ __forceinline__ void drain() {
    asm volatile("s_waitcnt vmcnt(0) lgkmcnt(0)" ::: "memory");
    __syncthreads();
}

// ---------------------------------------------------------------------------
// cbar: 32-chain-block barrier via all-to-all distributed flags.
// Each block stores chf[b*FPAD]=nph (own line); lanes 0..31 poll 32 distinct
// lines (divergent exit). No shared hot line.
// ---------------------------------------------------------------------------
__device__ __forceinline__ void cbar(int* chf, int b, int nph) {
    drain();
    int tid = threadIdx.x;
    if (tid == 0) ASTI(&chf[b * FPAD], nph);
    if (tid < 32) {
        while (ALDI(&chf[tid * FPAD]) < nph)
            __builtin_amdgcn_s_sleep(1);
    }
    __syncthreads();
}

// ---------------------------------------------------------------------------
// wait_zd: chain block waits until zd[i] >= target for ALL i in [0,G2).
// 256 threads each poll ~3 distinct lines; __syncthreads_and combines.
// ---------------------------------------------------------------------------
__device__ __forceinline__ void wait_zd(int* zd, int target) {
    int tid = threadIdx.x;
    while (true) {
        int ok = 1;
        for (int i = tid; i < G2; i += 256)
            ok &= (ALDI(&zd[i * FPAD]) >= target);
        if (__syncthreads_and(ok)) break;
        __builtin_amdgcn_s_sleep(4);
    }
}

// ---------------------------------------------------------------------------
// small_gemm: outT = [tanh](inA @ WA [+ inB @ WB] + bias), feature-major.
// Ring-slot inputs: plain cached float4 loads (write-once slots -> first
// touch is L3-fresh). Outputs: coherent sc1 scalar stores. Math unchanged.
// ---------------------------------------------------------------------------
__device__ void small_gemm(const float* __restrict__ inA, const float* __restrict__ WA,
                           const float* __restrict__ inB, const float* __restrict__ WB,
                           const float* __restrict__ bias,
                           float* __restrict__ outT, float* __restrict__ hout,
                           int t, int do_tanh, int g, float* part /*32*257*/) {
    int tid = threadIdx.x;
    int j0 = g * 16;
    int jl = tid & 15, ks = tid >> 4;
    int k0 = ks * 32;
    int j = j0 + jl;

    float acc[32];
#pragma unroll
    for (int b = 0; b < 32; b++) acc[b] = 0.f;

    const float4* A4 = (const float4*)inA;
    if (inB != nullptr) {
        const float4* B4 = (const float4*)inB;
        for (int kk = 0; kk < 32; kk++) {
            int k = k0 + kk;
            float wa = WA[k * HID + j];
            float wb = WB[k * HID + j];
#pragma unroll
            for (int q = 0; q < 8; q++) {
                float4 a  = A4[k * 8 + q];
                float4 bv = B4[k * 8 + q];
                acc[q*4+0] = fmaf(a.x,  wa, acc[q*4+0]);
                acc[q*4+1] = fmaf(a.y,  wa, acc[q*4+1]);
                acc[q*4+2] = fmaf(a.z,  wa, acc[q*4+2]);
                acc[q*4+3] = fmaf(a.w,  wa, acc[q*4+3]);
                acc[q*4+0] = fmaf(bv.x, wb, acc[q*4+0]);
                acc[q*4+1] = fmaf(bv.y, wb, acc[q*4+1]);
                acc[q*4+2] = fmaf(bv.z, wb, acc[q*4+2]);
                acc[q*4+3] = fmaf(bv.w, wb, acc[q*4+3]);
            }
        }
    } else {
        for (int kk = 0; kk < 32; kk++) {
            int k = k0 + kk;
            float wa = WA[k * HID + j];
#pragma unroll
            for (int q = 0; q < 8; q++) {
                float4 a = A4[k * 8 + q];
                acc[q*4+0] = fmaf(a.x, wa, acc[q*4+0]);
                acc[q*4+1] = fmaf(a.y, wa, acc[q*4+1]);
                acc[q*4+2] = fmaf(a.z, wa, acc[q*4+2]);
                acc[q*4+3] = fmaf(a.w, wa, acc[q*4+3]);
            }
        }
    }

#pragma unroll
    for (int b = 0; b < 32; b++) part[b * 257 + tid] = acc[b];
    __syncthreads();

#pragma unroll
    for (int i = 0; i < 2; i++) {
        int o = i * 256 + tid;
        int jlo = o >> 5, bo = o & 31;
        float s = 0.f;
#pragma unroll
        for (int k2 = 0; k2 < 16; k2++) s += part[bo * 257 + k2 * 16 + jlo];
        s += bias[j0 + jlo];
        if (do_tanh) s = tanhf(s);
        AST(&outT[(j0 + jlo) * 32 + bo], s);
        if (hout != nullptr)
            hout[(size_t)bo * (TSTEPS * HID) + (size_t)t * HID + (j0 + jlo)] = s;
    }
    __syncthreads();   // protect shm reuse by next phase
}

// ---------------------------------------------------------------------------
// sm0_body: x1T = tanh(softmax_row(z0T)) for batch row b. 256 threads.
// ---------------------------------------------------------------------------
__device__ void sm0_body(const float* __restrict__ z0T, float* __restrict__ x1T,
                         float* shm, int b) {
    float* red = shm;
    int tid = threadIdx.x;
    float v0 = z0T[tid * 32 + b];
    float v1 = z0T[(tid + 256) * 32 + b];
    red[tid] = fmaxf(v0, v1);
    __syncthreads();
    for (int s = 128; s > 0; s >>= 1) {
        if (tid < s) red[tid] = fmaxf(red[tid], red[tid + s]);
        __syncthreads();
    }
    float M = red[0];
    __syncthreads();
    float e0 = expf(v0 - M), e1 = expf(v1 - M);
    red[tid] = e0 + e1;
    __syncthreads();
    for (int s = 128; s > 0; s >>= 1) {
        if (tid < s) red[tid] += red[tid + s];
        __syncthreads();
    }
    float inv = 1.0f / red[0];
    AST(&x1T[tid * 32 + b],         tanhf(e0 * inv));
    AST(&x1T[(tid + 256) * 32 + b], tanhf(e1 * inv));
    __syncthreads();
}

// ---------------------------------------------------------------------------
// comb_body: merge 786 partials for row b -> M, Sinv (coherent), argmax
// (first-occurrence tie-break), embed next token into xT (coherent stores).
// ---------------------------------------------------------------------------
__device__ void comb_body(float* __restrict__ pmax, float* __restrict__ psum,
                          int* __restrict__ parg,
                          float* __restrict__ Mws, float* __restrict__ Sinvws,
                          const float* __restrict__ emb, float* __restrict__ xT,
                          float* shm, int b) {
    float* redm  = shm;                 // 256
    float* reds  = shm + 256;           // 256
    int*   redc  = (int*)(shm + 512);   // 256
    int*   toksh = (int*)(shm + 768);   // 1
    int tid = threadIdx.x;

    float m = -1e30f;
    for (int g = tid; g < G2; g += 256) m = fmaxf(m, ALDF(&pmax[b * G2 + g]));
    redm[tid] = m;
    __syncthreads();
    for (int s = 128; s > 0; s >>= 1) {
        if (tid < s) redm[tid] = fmaxf(redm[tid], redm[tid + s]);
        __syncthreads();
    }
    float M = redm[0];

    float s_l = 0.f;
    int c_l = 0x7fffffff;
    for (int g = tid; g < G2; g += 256) {
        float pm = ALDF(&pmax[b * G2 + g]);
        s_l += ALDF(&psum[b * G2 + g]) * expf(pm - M);
        if (pm == M) c_l = min(c_l, ALDI(&parg[b * G2 + g]));
    }
    reds[tid] = s_l;
    redc[tid] = c_l;
    __syncthreads();
    for (int s = 128; s > 0; s >>= 1) {
        if (tid < s) {
            reds[tid] += reds[tid + s];
            redc[tid] = min(redc[tid], redc[tid + s]);
        }
        __syncthreads();
    }
    if (tid == 0) {
        AST(&Mws[b], M);
        AST(&Sinvws[b], 1.0f / reds[0]);
        toksh[0] = redc[0];
    }
    __syncthreads();
    int tok = toksh[0];
    for (int e = tid; e < HID; e += 256)
        AST(&xT[e * 32 + b], emb[(size_t)tok * EMB + e]);
    __syncthreads();
}

// ---------------------------------------------------------------------------
// z1_body: logits tile g = h1 @ V1 + c1; raw store + per-tile softmax
// partials; overlapped normalization of step t-1's y using LDS-cached
// Msh/Ssh (NOT per-use sc1 loads — round-3 hotspot: ~50k wave-requests/step
// on 8 lines). Math identical to rounds 1-3.
// ---------------------------------------------------------------------------
__device__ void z1_body(const float* __restrict__ h1T, const float* __restrict__ V1w,
                        const float* __restrict__ c1, float* __restrict__ yout,
                        float* __restrict__ pmax, float* __restrict__ psum,
                        int* __restrict__ parg,
                        const float* __restrict__ Msh, const float* __restrict__ Ssh,
                        int t, int do_ywr, int g, float* partz /*32*256*/) {
    int tid = threadIdx.x;
    int j0 = g * JT2;
    int jl = tid & 63, ks = tid >> 6;
    int k0 = ks * 128;
    int jv = j0 + jl;
    int jc = jv < VOCAB ? jv : (VOCAB - 1);

    // issue prior-step y loads early; finished after the matmul
    float yv[8];
    if (do_ywr) {
#pragma unroll
        for (int i = 0; i < 8; i++) {
            int o = i * 256 + tid;
            int bo = o >> 6;
            int jj = j0 + (o & 63);
            if (jj < VOCAB)
                yv[i] = yout[((size_t)bo * TSTEPS + (t - 1)) * VOCAB + jj];
        }
    }

    float acc[32];
#pragma unroll
    for (int b = 0; b < 32; b++) acc[b] = 0.f;

    const float4* h4 = (const float4*)h1T;
    const float*  vp = V1w + (size_t)k0 * VOCAB + jc;
    for (int kk = 0; kk < 128; kk += 8) {
        float v[8];
#pragma unroll
        for (int u = 0; u < 8; u++) v[u] = vp[(size_t)(kk + u) * VOCAB];
#pragma unroll
        for (int u = 0; u < 8; u++) {
            int kb = __builtin_amdgcn_readfirstlane(k0 + kk + u) * 8;
            float4 hq[4];
#pragma unroll
            for (int q = 0; q < 4; q++) hq[q] = h4[kb + q];
#pragma unroll
            for (int q = 0; q < 4; q++) {
                acc[q*4+0] = fmaf(hq[q].x, v[u], acc[q*4+0]);
                acc[q*4+1] = fmaf(hq[q].y, v[u], acc[q*4+1]);
                acc[q*4+2] = fmaf(hq[q].z, v[u], acc[q*4+2]);
                acc[q*4+3] = fmaf(hq[q].w, v[u], acc[q*4+3]);
            }
#pragma unroll
            for (int q = 0; q < 4; q++) hq[q] = h4[kb + 4 + q];
#pragma unroll
            for (int q = 0; q < 4; q++) {
                acc[16+q*4+0] = fmaf(hq[q].x, v[u], acc[16+q*4+0]);
                acc[16+q*4+1] = fmaf(hq[q].y, v[u], acc[16+q*4+1]);
                acc[16+q*4+2] = fmaf(hq[q].z, v[u], acc[16+q*4+2]);
                acc[16+q*4+3] = fmaf(hq[q].w, v[u], acc[16+q*4+3]);
            }
        }
    }

#pragma unroll
    for (int b = 0; b < 32; b++) partz[b * 256 + tid] = acc[b];

    // finish y normalization for step t-1 (Msh/Ssh from LDS)
    if (do_ywr) {
#pragma unroll
        for (int i = 0; i < 8; i++) {
            int o = i * 256 + tid;
            int bo = o >> 6;
            int jj = j0 + (o & 63);
            if (jj < VOCAB)
                yout[((size_t)bo * TSTEPS + (t - 1)) * VOCAB + jj]
                    = expf(yv[i] - Msh[bo]) * Ssh[bo];
        }
    }
    __syncthreads();

    // combine 4 K-slices, add bias, store raw logits; wave-butterfly stats
    int w = tid >> 6;
#pragma unroll
    for (int i = 0; i < 8; i++) {
        int bo = i * 4 + w;
        float s = partz[bo * 256 + jl]
                + partz[bo * 256 + 64 + jl]
                + partz[bo * 256 + 128 + jl]
                + partz[bo * 256 + 192 + jl];
        int jj = j0 + jl;
        float z;
        if (jj < VOCAB) {
            z = s + c1[jj];
            yout[((size_t)bo * TSTEPS + t) * VOCAB + jj] = z;
        } else {
            z = -1e30f;
        }
        float m = z; int a = jj;
#pragma unroll
        for (int d = 1; d < 64; d <<= 1) {
            float mo = __shfl_xor(m, d);
            int   ao = __shfl_xor(a, d);
            if (mo > m || (mo == m && ao < a)) { m = mo; a = ao; }
        }
        float e = expf(z - m);
        float ss = e;
#pragma unroll
        for (int d = 1; d < 64; d <<= 1) ss += __shfl_xor(ss, d);
        if (jl == 0) {
            AST(&pmax[bo * G2 + g], m);
            AST(&psum[bo * G2 + g], ss);
            ASTI(&parg[bo * G2 + g], a);
        }
    }
    __syncthreads();   // protect partz reuse
}

// ---------------------------------------------------------------------------
// k_all: entire 64-step decode in ONE persistent kernel, fence-free,
// contention-free sync. Grid 786 x 256; LDS ~33.2 KB; launch_bounds(256,4)
// -> 4 blocks/CU -> 1024 slots >= 786 (no deadlock).
// ---------------------------------------------------------------------------
__global__ __launch_bounds__(256, 4) void k_all(
    const int* __restrict__ x, const float* __restrict__ h_prev,
    const float* __restrict__ emb,
    const float* __restrict__ U0, const float* __restrict__ W0, const float* __restrict__ b0,
    const float* __restrict__ V0, const float* __restrict__ c0,
    const float* __restrict__ U1, const float* __restrict__ W1, const float* __restrict__ b1,
    const float* __restrict__ V1, const float* __restrict__ c1,
    float* __restrict__ hout, float* __restrict__ yout,
    float* xTr, float* h0r, float* h1r, float* z0r, float* x1r,
    float* pmax, float* psum, int* parg,
    float* Mws, float* Sinvws,
    int* chf, int* go, int* zd)
{
    __shared__ float shm[32 * 257];
    __shared__ float Msh[32], Ssh[32];
    const int blk = blockIdx.x;
    const int tid = threadIdx.x;
    const bool chain = (blk < 32);
    int nph = 0;

    if (chain) {
        int b = blk;
        int tok = x[b];
        for (int e = tid; e < HID; e += 256) {
            AST(&xTr[e * 32 + b], emb[(size_t)tok * EMB + e]);   // xT slot 0
            float hp = h_prev[b * HID + e];
            AST(&h0r[e * 32 + b], hp);                           // h0 slot 0
            AST(&h1r[e * 32 + b], hp);                           // h1 slot 0
        }
        nph++; cbar(chf, blk, nph);
    }

    for (int t = 0; t < TSTEPS; t++) {
        float* xT_t = xTr + (size_t)t * NSLOT;
        float* h0p  = h0r + (size_t)t * NSLOT;
        float* h0n  = h0r + (size_t)(t + 1) * NSLOT;
        float* h1p  = h1r + (size_t)t * NSLOT;
        float* h1n  = h1r + (size_t)(t + 1) * NSLOT;
        float* z0t  = z0r + (size_t)t * NSLOT;
        float* x1t  = x1r + (size_t)t * NSLOT;

        if (chain) {
            if (t > 0) {
                wait_zd(zd, t);                  // all step-(t-1) partials
                comb_body(pmax, psum, parg, Mws, Sinvws, emb, xT_t, shm, blk);
                nph++; cbar(chf, blk, nph);
            }
            small_gemm(xT_t, U0, h0p, W0, b0, h0n, nullptr, t, 1, blk, shm);
            nph++; cbar(chf, blk, nph);
            small_gemm(h0n, V0, nullptr, nullptr, c0, z0t, nullptr, t, 0, blk, shm);
            nph++; cbar(chf, blk, nph);
            sm0_body(z0t, x1t, shm, blk);
            nph++; cbar(chf, blk, nph);
            small_gemm(x1t, U1, h1p, W1, b1, h1n, hout, t, 1, blk, shm);
            nph++; cbar(chf, blk, nph);          // all chain work drained
            // broadcast: each chain block releases its 1/32 slice of go lines
            if (tid < 25) {
                int i = blk + 32 * tid;
                if (i < G2) ASTI(&go[i * FPAD], t + 1);
            }
        }

        // ---- all blocks: wait own go line (1 poller per line)
        if (tid == 0) {
            while (ALDI(&go[blk * FPAD]) < t + 1)
                __builtin_amdgcn_s_sleep(4);
        }
        __syncthreads();
        // cache Mws/Sinv once per block (coalesced, 2 wave-requests)
        if (t > 0 && tid < 32) {
            Msh[tid] = ALDF(&Mws[tid]);
            Ssh[tid] = ALDF(&Sinvws[tid]);
        }
        __syncthreads();

        z1_body(h1n, V1, c1, yout, pmax, psum, parg, Msh, Ssh,
                t, (t > 0) ? 1 : 0, blk, shm);

        drain();                                  // partials at L3
        if (tid == 0) ASTI(&zd[blk * FPAD], t + 1);
    }

    if (chain) {
        wait_zd(zd, TSTEPS);
        // final comb: only Mws/Sinv needed; xT slot 64 is scratch
        comb_body(pmax, psum, parg, Mws, Sinvws, emb,
                  xTr + (size_t)TSTEPS * NSLOT, shm, blk);
        nph++; cbar(chf, blk, nph);
        if (tid < 25) {
            int i = blk + 32 * tid;
            if (i < G2) ASTI(&go[i * FPAD], TSTEPS + 1);
        }
    }
    if (tid == 0) {
        while (ALDI(&go[blk * FPAD]) < TSTEPS + 1)
            __builtin_amdgcn_s_sleep(4);
    }
    __syncthreads();
    if (tid < 32) {
        Msh[tid] = ALDF(&Mws[tid]);
        Ssh[tid] = ALDF(&Sinvws[tid]);
    }
    __syncthreads();
    // final normalize of step 63's y (tile g = blk; rows this block wrote)
    {
        int j0 = blk * JT2;
#pragma unroll
        for (int i = 0; i < 8; i++) {
            int o = i * 256 + tid;
            int bo = o >> 6;
            int jj = j0 + (o & 63);
            if (jj < VOCAB) {
                size_t idx = ((size_t)bo * TSTEPS + (TSTEPS - 1)) * VOCAB + jj;
                yout[idx] = expf(yout[idx] - Msh[bo]) * Ssh[bo];
            }
        }
    }
}

// ---------------------------------------------------------------------------
extern "C" void kernel_launch(void* const* d_in, const int* in_sizes, int n_in,
                              void* d_out, int out_size, void* d_ws, size_t ws_size,
                              hipStream_t stream) {
    const int*   x      = (const int*)d_in[0];
    // d_in[1] = max_len (64), d_in[2] = eos_token_id — unused by reference math
    const float* h_prev = (const float*)d_in[3];
    const float* emb    = (const float*)d_in[4];
    const float* U0 = (const float*)d_in[5];
    const float* W0 = (const float*)d_in[6];
    const float* b0 = (const float*)d_in[7];
    const float* V0 = (const float*)d_in[8];
    const float* c0 = (const float*)d_in[9];
    const float* U1 = (const float*)d_in[10];
    const float* W1 = (const float*)d_in[11];
    const float* b1 = (const float*)d_in[12];
    const float* V1 = (const float*)d_in[13];
    const float* c1 = (const float*)d_in[14];

    float* out  = (float*)d_out;
    float* hout = out;                                   // (32, 64, 512)
    float* yout = out + (size_t)BATCH * TSTEPS * HID;    // (32, 64, 50257)

    // workspace carve: write-once rings (t-indexed, no wrap within a launch)
    float* w = (float*)d_ws;
    float* xTr  = w; w += (size_t)(TSTEPS + 1) * NSLOT;  // slots 0..64
    float* h0r  = w; w += (size_t)(TSTEPS + 1) * NSLOT;
    float* h1r  = w; w += (size_t)(TSTEPS + 1) * NSLOT;
    float* z0r  = w; w += (size_t)TSTEPS * NSLOT;        // slots 0..63
    float* x1r  = w; w += (size_t)TSTEPS * NSLOT;
    float* pmax = w; w += 32 * G2;
    float* psum = w; w += 32 * G2;
    float* Mws  = w; w += 32;
    float* Sinvws = w; w += 32;
    int*   parg = (int*)w; w += 32 * G2;
    // flag lines (zeroed every launch/replay): chf 32, go 786, zd 786
    int*   chf  = (int*)w;
    int*   go   = chf + 32 * FPAD;
    int*   zd   = go + G2 * FPAD;
    size_t flagInts = (size_t)(32 + G2 + G2) * FPAD;

    hipMemsetAsync(chf, 0, flagInts * sizeof(int), stream);

    hipLaunchKernelGGL(k_all, dim3(G2), dim3(256), 0, stream,
                       x, h_prev, emb,
                       U0, W0, b0, V0, c0, U1, W1, b1, V1, c1,
                       hout, yout,
                       xTr, h0r, h1r, z0r, x1r,
                       pmax, psum, parg, Mws, Sinvws,
                       chf, go, zd);
}

// Round 5
// 7233.682 us; speedup vs baseline: 3.4522x; 2.3199x over previous
//
#include <hip/hip_runtime.h>

#define BATCH 32
#define HID   512
#define EMB   512
#define VOCAB 50257
#define TSTEPS 64
#define JT2   64            // columns per logits block
#define G2    786           // ceil(VOCAB / JT2)

// ===========================================================================
// k_chain: ONE BLOCK PER BATCH ROW runs the entire recurrent chain for step
// t: comb(t-1) -> embed token -> h0 -> z0 -> softmax -> x1 -> h1.
// The chain is batch-row-separable, so there is NO cross-block dependency
// inside a step: only __syncthreads(), no grid sync, no intermediate global
// state (row vectors live in LDS). This replaces 4 of round-1's 6 launches.
//
// GEMM form (per 512x512 matrix): 512 threads = 4 K-slices x 128 col-quads;
// weights read as float4 (coalesced 1 KiB/wave-instr, L2-resident), inputs
// broadcast from LDS; 4-slice partials combined through LDS. ~2 us/matrix.
// ===========================================================================
__global__ __launch_bounds__(512) void k_chain(
    const int* __restrict__ x, const float* __restrict__ h_prev,
    const float* __restrict__ emb,
    const float* __restrict__ U0, const float* __restrict__ W0, const float* __restrict__ b0,
    const float* __restrict__ V0, const float* __restrict__ c0,
    const float* __restrict__ U1, const float* __restrict__ W1, const float* __restrict__ b1,
    const float* __restrict__ pmax, const float* __restrict__ psum, const int* __restrict__ parg,
    float* __restrict__ Mws, float* __restrict__ Sinvws,
    float* __restrict__ h0row, const float* __restrict__ h1Tp, float* __restrict__ h1Tn,
    float* __restrict__ hout, int t, int only_comb)
{
    __shared__ float x_sh[512], hp0_sh[512], h0_sh[512], x1_sh[512], hp1_sh[512];
    __shared__ float part[2048];            // 4 K-slices x 512 cols
    __shared__ float red8[8];
    __shared__ int   redi8[8];

    const int b    = blockIdx.x;
    const int tid  = threadIdx.x;
    const int lane = tid & 63;
    const int wid  = tid >> 6;
    const int ks   = tid >> 7;              // K-slice 0..3 (128 k each)
    const int c    = tid & 127;             // col-quad 0..127 (cols 4c..4c+3)

    if (t == 0) {
        hp1_sh[tid] = h_prev[b * HID + tid];
        int tok = x[b];
        x_sh[tid]   = emb[(size_t)tok * EMB + tid];
        hp0_sh[tid] = h_prev[b * HID + tid];
    } else {
        if (!only_comb) hp1_sh[tid] = h1Tp[tid * 32 + b];
        // ---- comb(t-1): merge this row's 786 tile-partials -> M, Sinv, argmax
        float m = -1e30f;
        for (int g = tid; g < G2; g += 512) m = fmaxf(m, pmax[b * G2 + g]);
#pragma unroll
        for (int d = 1; d < 64; d <<= 1) m = fmaxf(m, __shfl_xor(m, d));
        if (lane == 0) red8[wid] = m;
        __syncthreads();
        float M = red8[0];
#pragma unroll
        for (int w2 = 1; w2 < 8; w2++) M = fmaxf(M, red8[w2]);
        __syncthreads();                     // red8 reuse
        float s = 0.f; int cl = 0x7fffffff;
        for (int g = tid; g < G2; g += 512) {
            float pm = pmax[b * G2 + g];
            s += psum[b * G2 + g] * expf(pm - M);
            if (pm == M) cl = min(cl, parg[b * G2 + g]);
        }
#pragma unroll
        for (int d = 1; d < 64; d <<= 1) {
            s += __shfl_xor(s, d);
            cl = min(cl, __shfl_xor(cl, d));
        }
        if (lane == 0) { red8[wid] = s; redi8[wid] = cl; }
        __syncthreads();
        float S = red8[0]; int tok = redi8[0];
#pragma unroll
        for (int w2 = 1; w2 < 8; w2++) { S += red8[w2]; tok = min(tok, redi8[w2]); }
        if (tid == 0) { Mws[b] = M; Sinvws[b] = 1.0f / S; }
        if (only_comb) return;               // final-step variant: stats only
        x_sh[tid]   = emb[(size_t)tok * EMB + tid];
        hp0_sh[tid] = h0row[b * HID + tid];
        __syncthreads();                     // red8/redi8 reuse + x_sh fill
    }
    __syncthreads();

    const float4* U04 = (const float4*)U0;
    const float4* W04 = (const float4*)W0;
    const float4* V04 = (const float4*)V0;
    const float4* U14 = (const float4*)U1;
    const float4* W14 = (const float4*)W1;
    const int k0 = ks * 128;

    // ---- h0 = tanh(x @ U0 + hp0 @ W0 + b0)
    {
        float a0 = 0.f, a1 = 0.f, a2 = 0.f, a3 = 0.f;
#pragma unroll 4
        for (int kk = 0; kk < 128; kk++) {
            int k = k0 + kk;
            float xv = x_sh[k], hv = hp0_sh[k];
            float4 u = U04[(size_t)k * 128 + c];
            float4 w = W04[(size_t)k * 128 + c];
            a0 = fmaf(hv, w.x, fmaf(xv, u.x, a0));
            a1 = fmaf(hv, w.y, fmaf(xv, u.y, a1));
            a2 = fmaf(hv, w.z, fmaf(xv, u.z, a2));
            a3 = fmaf(hv, w.w, fmaf(xv, u.w, a3));
        }
        ((float4*)part)[ks * 128 + c] = make_float4(a0, a1, a2, a3);
        __syncthreads();
        float v = part[tid] + part[512 + tid] + part[1024 + tid] + part[1536 + tid]
                + b0[tid];
        v = tanhf(v);
        h0_sh[tid] = v;
        h0row[b * HID + tid] = v;            // persisted for next step's comb path
        __syncthreads();
    }

    // ---- z0 = h0 @ V0 + c0 ; x1 = tanh(softmax(z0))
    {
        float a0 = 0.f, a1 = 0.f, a2 = 0.f, a3 = 0.f;
#pragma unroll 4
        for (int kk = 0; kk < 128; kk++) {
            int k = k0 + kk;
            float hv = h0_sh[k];
            float4 vq = V04[(size_t)k * 128 + c];
            a0 = fmaf(hv, vq.x, a0);
            a1 = fmaf(hv, vq.y, a1);
            a2 = fmaf(hv, vq.z, a2);
            a3 = fmaf(hv, vq.w, a3);
        }
        ((float4*)part)[ks * 128 + c] = make_float4(a0, a1, a2, a3);
        __syncthreads();
        float z = part[tid] + part[512 + tid] + part[1024 + tid] + part[1536 + tid]
                + c0[tid];
        // block-wide softmax over 512 cols (wave butterfly + 8-wave merge)
        float m = z;
#pragma unroll
        for (int d = 1; d < 64; d <<= 1) m = fmaxf(m, __shfl_xor(m, d));
        if (lane == 0) red8[wid] = m;
        __syncthreads();
        float M2 = red8[0];
#pragma unroll
        for (int w2 = 1; w2 < 8; w2++) M2 = fmaxf(M2, red8[w2]);
        __syncthreads();                     // red8 reuse
        float e = expf(z - M2);
        float s2 = e;
#pragma unroll
        for (int d = 1; d < 64; d <<= 1) s2 += __shfl_xor(s2, d);
        if (lane == 0) red8[wid] = s2;
        __syncthreads();
        float S2 = red8[0];
#pragma unroll
        for (int w2 = 1; w2 < 8; w2++) S2 += red8[w2];
        x1_sh[tid] = tanhf(e * (1.0f / S2));
        __syncthreads();
    }

    // ---- h1 = tanh(x1 @ U1 + hp1 @ W1 + b1)
    {
        float a0 = 0.f, a1 = 0.f, a2 = 0.f, a3 = 0.f;
#pragma unroll 4
        for (int kk = 0; kk < 128; kk++) {
            int k = k0 + kk;
            float xv = x1_sh[k], hv = hp1_sh[k];
            float4 u = U14[(size_t)k * 128 + c];
            float4 w = W14[(size_t)k * 128 + c];
            a0 = fmaf(hv, w.x, fmaf(xv, u.x, a0));
            a1 = fmaf(hv, w.y, fmaf(xv, u.y, a1));
            a2 = fmaf(hv, w.z, fmaf(xv, u.z, a2));
            a3 = fmaf(hv, w.w, fmaf(xv, u.w, a3));
        }
        ((float4*)part)[ks * 128 + c] = make_float4(a0, a1, a2, a3);
        __syncthreads();
        float v = part[tid] + part[512 + tid] + part[1024 + tid] + part[1536 + tid]
                + b1[tid];
        v = tanhf(v);
        h1Tn[tid * 32 + b] = v;              // feature-major for k_z1
        hout[(size_t)b * (TSTEPS * HID) + (size_t)t * HID + tid] = v;
    }
}

// ===========================================================================
// k_z1: logits z1 = h1 @ V1 + c1 (raw store) + per-tile softmax partials;
// overlapped normalization of step t-1's y. VERBATIM the round-1 validated
// kernel (plain cached loads/stores; visibility via dispatch boundaries).
// LDS exactly 32 KiB + launch_bounds(256,4) -> 4 blocks/CU -> 1024 >= 786.
// ===========================================================================
__global__ __launch_bounds__(256, 4) void k_z1(const float* __restrict__ h1T,
                                               const float* __restrict__ V1w,
                                               const float* __restrict__ c1,
                                               float* __restrict__ yout,
                                               float* __restrict__ pmax,
                                               float* __restrict__ psum,
                                               int* __restrict__ parg,
                                               const float* __restrict__ Mws,
                                               const float* __restrict__ Sinvws,
                                               int t, int do_ywr) {
    __shared__ float partz[32 * 256];
    int tid = threadIdx.x;
    int g = blockIdx.x;
    int j0 = g * JT2;
    int jl = tid & 63, ks = tid >> 6;
    int k0 = ks * 128;
    int jv = j0 + jl;
    int jc = jv < VOCAB ? jv : (VOCAB - 1);

    // issue prior-step y loads early; finished after the matmul
    float yv[8];
    if (do_ywr) {
#pragma unroll
        for (int i = 0; i < 8; i++) {
            int o = i * 256 + tid;
            int bo = o >> 6;
            int jj = j0 + (o & 63);
            if (jj < VOCAB)
                yv[i] = yout[((size_t)bo * TSTEPS + (t - 1)) * VOCAB + jj];
        }
    }

    float acc[32];
#pragma unroll
    for (int b = 0; b < 32; b++) acc[b] = 0.f;

    const float4* h4 = (const float4*)h1T;
    const float*  vp = V1w + (size_t)k0 * VOCAB + jc;
    for (int kk = 0; kk < 128; kk += 8) {
        float v[8];
#pragma unroll
        for (int u = 0; u < 8; u++) v[u] = vp[(size_t)(kk + u) * VOCAB];
#pragma unroll
        for (int u = 0; u < 8; u++) {
            int kb = __builtin_amdgcn_readfirstlane(k0 + kk + u) * 8;
            float4 hq[4];
#pragma unroll
            for (int q = 0; q < 4; q++) hq[q] = h4[kb + q];
#pragma unroll
            for (int q = 0; q < 4; q++) {
                acc[q*4+0] = fmaf(hq[q].x, v[u], acc[q*4+0]);
                acc[q*4+1] = fmaf(hq[q].y, v[u], acc[q*4+1]);
                acc[q*4+2] = fmaf(hq[q].z, v[u], acc[q*4+2]);
                acc[q*4+3] = fmaf(hq[q].w, v[u], acc[q*4+3]);
            }
#pragma unroll
            for (int q = 0; q < 4; q++) hq[q] = h4[kb + 4 + q];
#pragma unroll
            for (int q = 0; q < 4; q++) {
                acc[16+q*4+0] = fmaf(hq[q].x, v[u], acc[16+q*4+0]);
                acc[16+q*4+1] = fmaf(hq[q].y, v[u], acc[16+q*4+1]);
                acc[16+q*4+2] = fmaf(hq[q].z, v[u], acc[16+q*4+2]);
                acc[16+q*4+3] = fmaf(hq[q].w, v[u], acc[16+q*4+3]);
            }
        }
    }

#pragma unroll
    for (int b = 0; b < 32; b++) partz[b * 256 + tid] = acc[b];

    // finish y normalization for step t-1 (independent of the barrier)
    if (do_ywr) {
#pragma unroll
        for (int i = 0; i < 8; i++) {
            int o = i * 256 + tid;
            int bo = o >> 6;
            int jj = j0 + (o & 63);
            if (jj < VOCAB)
                yout[((size_t)bo * TSTEPS + (t - 1)) * VOCAB + jj]
                    = expf(yv[i] - Mws[bo]) * Sinvws[bo];
        }
    }
    __syncthreads();

    // combine 4 K-slices, add bias, store raw logits; wave-butterfly stats
    int w = tid >> 6;
#pragma unroll
    for (int i = 0; i < 8; i++) {
        int bo = i * 4 + w;
        float s = partz[bo * 256 + jl]
                + partz[bo * 256 + 64 + jl]
                + partz[bo * 256 + 128 + jl]
                + partz[bo * 256 + 192 + jl];
        int jj = j0 + jl;
        float z;
        if (jj < VOCAB) {
            z = s + c1[jj];
            yout[((size_t)bo * TSTEPS + t) * VOCAB + jj] = z;
        } else {
            z = -1e30f;   // pad lanes: never the max, exp -> 0
        }
        float m = z; int a = jj;
#pragma unroll
        for (int d = 1; d < 64; d <<= 1) {
            float mo = __shfl_xor(m, d);
            int   ao = __shfl_xor(a, d);
            if (mo > m || (mo == m && ao < a)) { m = mo; a = ao; }
        }
        float e = expf(z - m);
        float ss = e;
#pragma unroll
        for (int d = 1; d < 64; d <<= 1) ss += __shfl_xor(ss, d);
        if (jl == 0) {
            pmax[bo * G2 + g] = m;
            psum[bo * G2 + g] = ss;
            parg[bo * G2 + g] = a;
        }
    }
}

// ---------------------------------------------------------------------------
// k_ywr: final normalize of step 63's y.
// ---------------------------------------------------------------------------
__global__ __launch_bounds__(256) void k_ywr(float* __restrict__ yout,
                                             const float* __restrict__ Mws,
                                             const float* __restrict__ Sinvws) {
    int b = blockIdx.y;
    int v = blockIdx.x * 256 + threadIdx.x;
    if (v < VOCAB) {
        size_t idx = ((size_t)b * TSTEPS + (TSTEPS - 1)) * VOCAB + v;
        yout[idx] = expf(yout[idx] - Mws[b]) * Sinvws[b];
    }
}

// ---------------------------------------------------------------------------
extern "C" void kernel_launch(void* const* d_in, const int* in_sizes, int n_in,
                              void* d_out, int out_size, void* d_ws, size_t ws_size,
                              hipStream_t stream) {
    const int*   x      = (const int*)d_in[0];
    // d_in[1] = max_len (64), d_in[2] = eos_token_id — unused by reference math
    const float* h_prev = (const float*)d_in[3];
    const float* emb    = (const float*)d_in[4];
    const float* U0 = (const float*)d_in[5];
    const float* W0 = (const float*)d_in[6];
    const float* b0 = (const float*)d_in[7];
    const float* V0 = (const float*)d_in[8];
    const float* c0 = (const float*)d_in[9];
    const float* U1 = (const float*)d_in[10];
    const float* W1 = (const float*)d_in[11];
    const float* b1 = (const float*)d_in[12];
    const float* V1 = (const float*)d_in[13];
    const float* c1 = (const float*)d_in[14];

    float* out  = (float*)d_out;
    float* hout = out;                                   // (32, 64, 512)
    float* yout = out + (size_t)BATCH * TSTEPS * HID;    // (32, 64, 50257)

    // workspace carve (all offsets multiples of 32 floats -> 16B aligned)
    float* w = (float*)d_ws;
    float* h0row = w; w += BATCH * HID;     // row-major h0 state (chain-private)
    float* h1Ta  = w; w += HID * 32;        // feature-major h1 double buffer
    float* h1Tb  = w; w += HID * 32;
    float* pmax  = w; w += 32 * G2;
    float* psum  = w; w += 32 * G2;
    float* Mws   = w; w += 32;
    float* Sinvws= w; w += 32;
    int*   parg  = (int*)w; w += 32 * G2;

    for (int t = 0; t < TSTEPS; t++) {
        const float* h1p = (t & 1) ? h1Tb : h1Ta;
        float*       h1n = (t & 1) ? h1Ta : h1Tb;

        // full small chain for step t (comb(t-1) -> h0 -> z0 -> sm0 -> h1)
        hipLaunchKernelGGL(k_chain, dim3(32), dim3(512), 0, stream,
                           x, h_prev, emb,
                           U0, W0, b0, V0, c0, U1, W1, b1,
                           pmax, psum, parg, Mws, Sinvws,
                           h0row, h1p, h1n, hout, t, 0);
        // z1 = h1 @ V1 + c1 (+ partials; + normalize y of t-1)
        hipLaunchKernelGGL(k_z1, dim3(G2), dim3(256), 0, stream,
                           h1n, V1, c1, yout, pmax, psum, parg,
                           Mws, Sinvws, t, (t > 0) ? 1 : 0);
    }
    // final comb (stats for t=63 only; only_comb=1 returns after Mws/Sinv)
    hipLaunchKernelGGL(k_chain, dim3(32), dim3(512), 0, stream,
                       x, h_prev, emb,
                       U0, W0, b0, V0, c0, U1, W1, b1,
                       pmax, psum, parg, Mws, Sinvws,
                       h0row, h1Ta, h1Tb, hout, TSTEPS, 1);
    // normalize last step's y
    hipLaunchKernelGGL(k_ywr, dim3(dim3((VOCAB + 255) / 256, 32)), dim3(256), 0, stream,
                       yout, Mws, Sinvws);
}